// Round 3
// baseline (450.211 us; speedup 1.0000x reference)
//
#include <hip/hip_runtime.h>

// BSplineLayer: piecewise-linear spline eval.
// u: [4096,64,256] f32 (channel = fastest axis), knots/coefs: [256,64] f32.
// out[e] = c0 + (x-k0)/(k1-k0+eps) * (c1-c0), segment from searchsorted(left).
//
// v3 (LDS-throughput round):
//  - Post-mortem v2: raising occupancy 16->32 waves/CU REGRESSED (+9us) ->
//    kernel is throughput-bound on a per-CU resource, not wave-starved.
//    Arithmetic: 16 scattered ds_read_b32/thread-iter at ~4-5-way conflict
//    ~= 2300-2600 cyc/CU per 16-wave round vs ~3140 cyc HBM budget -> LDS
//    issue/conflict time barely hidden under the stream.
//  - Fix: paired LDS table sP[c][j] = (k[j],k[j+1],c[j],c[j+1]) (float4,
//    j=0..62) -> ONE aligned ds_read_b128 per element instead of four
//    ds_read_b32. 4x fewer LDS instructions/conflict opportunities.
//  - 32-channel groups (8 groups): 32KB LDS/block -> 4 blocks/CU resident
//    (grid 1024 = 4/CU), 16 waves/CU — same residency as the best kernel.
//  - v2's nt hints + prefetch reverted (no measurable win, possible harm).
//
// Carried over from v1 (best measured 434us):
//  - float4 I/O, lanes cover contiguous segments -> coalesced.
//  - Analytic segment guess + exact-compare fixup loops (exact for uniform
//    knots, correct for any sorted knots, ~0 fixup iterations here).

#define EPS 1e-6f
#define NCH_GROUP 32
#define NGROUPS 8
#define BLOCKS_PER_GROUP 128
#define ROWS_PER_TILE 32   // 256 threads / 8 col4-slots

typedef float f32x4 __attribute__((ext_vector_type(4)));

__global__ __launch_bounds__(256) void bspline_kernel(
    const float* __restrict__ u, const float* __restrict__ knots,
    const float* __restrict__ coefs, float* __restrict__ out, int n_rows)
{
    // sP[c*64 + j] = (k[j], k[j+1], c[j], c[j+1]) for j in [0,62].
    // 32 * 64 * 16B = 32KB. Entry j=63 unused (j is clamped to <=62).
    __shared__ f32x4 sP[NCH_GROUP * 64];

    const int t = threadIdx.x;
    const int g = blockIdx.x & (NGROUPS - 1);   // channel group 0..7
    const int b = blockIdx.x >> 3;              // block index within group

    // Stage paired knot/coef table (reads are L2-resident after first blocks).
    const float* gk = knots + (size_t)g * NCH_GROUP * 64;
    const float* gc = coefs + (size_t)g * NCH_GROUP * 64;
    for (int i = t; i < NCH_GROUP * 63; i += 256) {
        int c = i / 63;
        int j = i - c * 63;
        f32x4 p;
        p.x = gk[c * 64 + j];
        p.y = gk[c * 64 + j + 1];
        p.z = gc[c * 64 + j];
        p.w = gc[c * 64 + j + 1];
        sP[(c << 6) + j] = p;
    }
    __syncthreads();

    const int col4 = t & 7;         // which float4 column within the group
    const int rsub = t >> 3;        // row 0..31 within a tile
    const int lc = col4 * 4;        // local channel base (0..28)

    // Per-channel analytic-guess parameters (fixed channels per thread).
    float kmin[4], scale[4];
#pragma unroll
    for (int cc = 0; cc < 4; ++cc) {
        float klo = sP[(lc + cc) << 6].x;        // k[0]
        float khi = sP[((lc + cc) << 6) + 62].y; // k[63]
        kmin[cc] = klo;
        scale[cc] = 63.0f * __builtin_amdgcn_rcpf(khi - klo);
    }

    const f32x4* u4 = (const f32x4*)u;
    f32x4* o4 = (f32x4*)out;
    const int colbase = g * 8 + col4;           // float4 column in [0,64)
    const int ntiles = n_rows / ROWS_PER_TILE;

    for (int rt = b; rt < ntiles; rt += BLOCKS_PER_GROUP) {
        int row = rt * ROWS_PER_TILE + rsub;
        size_t idx = (size_t)row * 64 + colbase;
        f32x4 x4 = u4[idx];
        f32x4 r;
#pragma unroll
        for (int cc = 0; cc < 4; ++cc) {
            float x = x4[cc];
            const f32x4* pc = &sP[(lc + cc) << 6];

            // Predictor: analytic segment guess (exact for uniform knots).
            float xs = (x - kmin[cc]) * scale[cc];
            int j = (int)xs;
            j = max(0, min(62, j));
            f32x4 p = pc[j];   // one ds_read_b128: k[j],k[j+1],c[j],c[j+1]
            // Corrector: exact-compare fixups. Final j satisfies
            // (j==0 || k[j] < x) && (j==62 || k[j+1] >= x)
            //   == clamp(searchsorted_left(k,x)-1, 0, 62) for any sorted k.
            while (j > 0 && p.x >= x) { --j; p = pc[j]; }
            while (j < 62 && p.y < x) { ++j; p = pc[j]; }

            float tt = (x - p.x) * __builtin_amdgcn_rcpf(p.y - p.x + EPS);
            r[cc] = fmaf(tt, p.w - p.z, p.z);
        }
        o4[idx] = r;
    }
}

extern "C" void kernel_launch(void* const* d_in, const int* in_sizes, int n_in,
                              void* d_out, int out_size, void* d_ws, size_t ws_size,
                              hipStream_t stream) {
    const float* u     = (const float*)d_in[0];
    const float* knots = (const float*)d_in[1];
    const float* coefs = (const float*)d_in[2];
    float* out = (float*)d_out;

    int n_rows = in_sizes[0] / 256;   // 262144 rows of 256 channels

    dim3 grid(NGROUPS * BLOCKS_PER_GROUP);   // 1024 blocks = 4/CU, 16 waves/CU
    dim3 block(256);
    bspline_kernel<<<grid, block, 0, stream>>>(u, knots, coefs, out, n_rows);
}

// Round 4
// 435.464 us; speedup vs baseline: 1.0339x; 1.0339x over previous
//
#include <hip/hip_runtime.h>

// BSplineLayer: piecewise-linear spline eval.
// u: [4096,64,256] f32 (channel = fastest axis), knots/coefs: [256,64] f32.
// out[e] = c0 + (x-k0)/(k1-k0+eps) * (c1-c0), segment from searchsorted(left).
//
// v4 (DRAM-contiguity round):
//  - Ladder evidence: v1 (64-ch groups, 256B row segments) 434us;
//    v2/v3 (32-ch groups, 128B segments) 443/450us. LDS restructures
//    regressed twice -> LDS is NOT the limiter. The monotone trend with
//    segment size says the residual vs the 6.3 TB/s copy ceiling is DRAM
//    page locality: each 1KB row is split across independent block-streams.
//  - Fix: 128-channel groups (2 groups). Each wave load = 512B contiguous
//    per row (32 lanes x 16B), 2x-4x bigger segments than v1/v3.
//  - To fit 2x 128x64 f32 tables in the 64KB static-LDS limit, replace the
//    stride-65 pad with a size-preserving XOR swizzle:
//      sK[c*64 + (j ^ (c&31))]  -> bank = (j ^ (c&31)) % 32,
//    same ~2-way random scatter as v1's (c+j)%32, zero size overhead.
//    (v3 lesson: b128 tables have only 8 bank-groups -> 8-way conflicts;
//    stay with 4x b32 reads per element like v1.)
//  - 512-thread blocks, 64KB LDS -> 2 blocks/CU = 16 waves/CU (v1's
//    residency, which beat 32 waves in v2).
//
// Carried over from v1:
//  - float4 I/O, coalesced; analytic segment guess + exact-compare fixup
//    loops (exact for uniform knots, correct for any sorted knots).

#define EPS 1e-6f
#define NCH_GROUP 128
#define NGROUPS 2
#define BLOCKS_PER_GROUP 256
#define ROWS_PER_TILE 16   // 512 threads / 32 col4-slots

typedef float f32x4 __attribute__((ext_vector_type(4)));

__global__ __launch_bounds__(512) void bspline_kernel(
    const float* __restrict__ u, const float* __restrict__ knots,
    const float* __restrict__ coefs, float* __restrict__ out, int n_rows)
{
    // XOR-swizzled tables: entry (c, j) lives at [c*64 + (j ^ (c&31))].
    // 2 * 128*64*4B = 64KB exactly (static LDS limit).
    __shared__ float sK[NCH_GROUP * 64];
    __shared__ float sC[NCH_GROUP * 64];

    const int t = threadIdx.x;
    const int g = blockIdx.x & (NGROUPS - 1);   // channel group 0..1
    const int b = blockIdx.x >> 1;              // block index within group

    // Stage this group's knots & coefs (8192 floats each, L2/L3-resident
    // after the first blocks) into swizzled LDS.
    const float* gk = knots + (size_t)g * NCH_GROUP * 64;
    const float* gc = coefs + (size_t)g * NCH_GROUP * 64;
    for (int i = t; i < NCH_GROUP * 64; i += 512) {
        int c = i >> 6;
        int j = i & 63;
        int s = (c << 6) | (j ^ (c & 31));
        sK[s] = gk[i];
        sC[s] = gc[i];
    }
    __syncthreads();

    const int col4 = t & 31;        // float4 column within the group
    const int rsub = t >> 5;        // row 0..15 within a tile
    const int lc = col4 * 4;        // local channel base (0..124)

    // Per-channel guess parameters (channels fixed per thread).
    float kmin[4], scale[4];
    int xm[4];
#pragma unroll
    for (int cc = 0; cc < 4; ++cc) {
        int c = lc + cc;
        int m = c & 31;
        xm[cc] = m;
        const float* kp = &sK[c << 6];
        float klo = kp[0 ^ m];
        float khi = kp[63 ^ m];
        kmin[cc] = klo;
        scale[cc] = 63.0f * __builtin_amdgcn_rcpf(khi - klo);
    }

    const f32x4* u4 = (const f32x4*)u;
    f32x4* o4 = (f32x4*)out;
    const int colbase = g * 32 + col4;          // float4 column in [0,64)
    const int ntiles = n_rows / ROWS_PER_TILE;

    for (int rt = b; rt < ntiles; rt += BLOCKS_PER_GROUP) {
        int row = rt * ROWS_PER_TILE + rsub;
        size_t idx = (size_t)row * 64 + colbase;
        f32x4 x4 = u4[idx];
        f32x4 r;
#pragma unroll
        for (int cc = 0; cc < 4; ++cc) {
            float x = x4[cc];
            const int m = xm[cc];
            const float* kp = &sK[(lc + cc) << 6];
            const float* cp = &sC[(lc + cc) << 6];

            // Predictor: analytic segment guess (exact for uniform knots).
            float xs = (x - kmin[cc]) * scale[cc];
            int j = (int)xs;
            j = max(0, min(62, j));
            float k0 = kp[j ^ m];
            float k1 = kp[(j + 1) ^ m];
            // Corrector: exact-compare fixups. Final j satisfies
            // (j==0 || k[j] < x) && (j==62 || k[j+1] >= x)
            //   == clamp(searchsorted_left(k,x)-1, 0, 62) for any sorted k.
            while (j > 0 && k0 >= x) { --j; k1 = k0; k0 = kp[j ^ m]; }
            while (j < 62 && k1 < x) { ++j; k0 = k1; k1 = kp[(j + 1) ^ m]; }

            float tt = (x - k0) * __builtin_amdgcn_rcpf(k1 - k0 + EPS);
            float c0 = cp[j ^ m];
            float c1 = cp[(j + 1) ^ m];
            r[cc] = fmaf(tt, c1 - c0, c0);
        }
        o4[idx] = r;
    }
}

extern "C" void kernel_launch(void* const* d_in, const int* in_sizes, int n_in,
                              void* d_out, int out_size, void* d_ws, size_t ws_size,
                              hipStream_t stream) {
    const float* u     = (const float*)d_in[0];
    const float* knots = (const float*)d_in[1];
    const float* coefs = (const float*)d_in[2];
    float* out = (float*)d_out;

    int n_rows = in_sizes[0] / 256;   // 262144 rows of 256 channels

    dim3 grid(NGROUPS * BLOCKS_PER_GROUP);   // 512 blocks = 2/CU, 16 waves/CU
    dim3 block(512);
    bspline_kernel<<<grid, block, 0, stream>>>(u, knots, coefs, out, n_rows);
}